// Round 1
// baseline (2730.619 us; speedup 1.0000x reference)
//
#include <hip/hip_runtime.h>
#include <math.h>

#define S_LEN 1024
#define BATCH 8
#define EMB 512
#define NHEAD 8
#define DHEAD 64
#define DHID 256
#define SDEPTH 48
#define SWIDTH 96
#define DFF 2048
#define DSS 128

// nonsat(x): solve y^3/3 + y = x by Newton (the reference's fixed-point iteration
// IS Newton for this equation; fully converged root == reference within ~1e-6).
__device__ __forceinline__ float nonsat_f(float x) {
  float y = x;
#pragma unroll
  for (int i = 0; i < 20; ++i) {
    float y2 = y * y;
    y = __fdividef(0.6666666667f * y * y2 + x, y2 + 1.0f);
  }
  return y;
}

// ---------------- generic fp32 GEMM: C[M,N] (+)= A[M,K] @ W[N,K]^T + bias ----
// perm: 0 identity; 1: A row = ((m&1023)<<3)|(m>>10)  (C rows (b,s), A rows (s,b))
//       2: A row = ((m&7)<<10)|(m>>3)                 (C rows (s,b), A rows (b,s))
// flags: bit0 = accumulate into C, bit1 = nonsat epilogue
__global__ __launch_bounds__(256)
void gemm_kernel(const float* __restrict__ A, int lda, int perm,
                 const float* __restrict__ W, int ldw,
                 const float* __restrict__ bias,
                 float* __restrict__ C,
                 int M, int N, int K, int flags) {
  __shared__ float As[16][68];
  __shared__ float Ws[16][68];
  int t = threadIdx.x;
  int tx = t & 15, ty = t >> 4;
  int m0 = blockIdx.y * 64, n0 = blockIdx.x * 64;
  int lr = t >> 2, lk = (t & 3) << 2;

  int mrow = m0 + lr;
  int arow = mrow;
  if (perm == 1)      arow = ((mrow & 1023) << 3) | (mrow >> 10);
  else if (perm == 2) arow = ((mrow & 7) << 10) | (mrow >> 3);
  const float* Ap = A + (size_t)arow * lda + lk;
  int nrow = n0 + lr;
  const float* Wp = W + (size_t)nrow * ldw + lk;
  bool wok = nrow < N;

  float acc[4][4] = {{0.f}};

  for (int k0 = 0; k0 < K; k0 += 16) {
    float4 av = *(const float4*)(Ap + k0);
    float4 wv = wok ? *(const float4*)(Wp + k0) : make_float4(0.f, 0.f, 0.f, 0.f);
    __syncthreads();
    As[lk + 0][lr] = av.x; As[lk + 1][lr] = av.y;
    As[lk + 2][lr] = av.z; As[lk + 3][lr] = av.w;
    Ws[lk + 0][lr] = wv.x; Ws[lk + 1][lr] = wv.y;
    Ws[lk + 2][lr] = wv.z; Ws[lk + 3][lr] = wv.w;
    __syncthreads();
#pragma unroll
    for (int k = 0; k < 16; ++k) {
      float a0 = As[k][ty * 4 + 0], a1 = As[k][ty * 4 + 1];
      float a2 = As[k][ty * 4 + 2], a3 = As[k][ty * 4 + 3];
      float w0 = Ws[k][tx * 4 + 0], w1 = Ws[k][tx * 4 + 1];
      float w2 = Ws[k][tx * 4 + 2], w3 = Ws[k][tx * 4 + 3];
      acc[0][0] += a0 * w0; acc[0][1] += a0 * w1; acc[0][2] += a0 * w2; acc[0][3] += a0 * w3;
      acc[1][0] += a1 * w0; acc[1][1] += a1 * w1; acc[1][2] += a1 * w2; acc[1][3] += a1 * w3;
      acc[2][0] += a2 * w0; acc[2][1] += a2 * w1; acc[2][2] += a2 * w2; acc[2][3] += a2 * w3;
      acc[3][0] += a3 * w0; acc[3][1] += a3 * w1; acc[3][2] += a3 * w2; acc[3][3] += a3 * w3;
    }
  }
#pragma unroll
  for (int i = 0; i < 4; ++i) {
    int m = m0 + ty * 4 + i;
#pragma unroll
    for (int j = 0; j < 4; ++j) {
      int n = n0 + tx * 4 + j;
      if (n < N) {
        float o = acc[i][j];
        if (bias) o += bias[n];
        size_t idx = (size_t)m * N + n;
        if (flags & 1) o += C[idx];
        if (flags & 2) o = nonsat_f(o);
        C[idx] = o;
      }
    }
  }
}

// --------- repack K,V from qkv (s,b,1536) into per-(b,h) contiguous slabs ----
__global__ __launch_bounds__(256)
void repack_kv(const float* __restrict__ qkv, float* __restrict__ Kc,
               float* __restrict__ Vc) {
  int i = blockIdx.x * 256 + threadIdx.x;  // float4 index, 1048576 total
  int d4 = i & 15;
  int t  = (i >> 4) & 1023;
  int h  = (i >> 14) & 7;
  int b  = i >> 17;
  const float4* src = (const float4*)qkv;
  size_t in_k = ((size_t)t * BATCH + b) * 384 + 128 + h * 16 + d4;
  size_t out  = (size_t)i;  // == ((b*8+h)*1024 + t)*16 + d4
  ((float4*)Kc)[out] = src[in_k];
  ((float4*)Vc)[out] = src[in_k + 128];
}

// --------- causal attention: one wave per (query s, b, h), scores in LDS -----
__global__ __launch_bounds__(64)
void attn_kernel(const float* __restrict__ qkv, const float* __restrict__ Kc,
                 const float* __restrict__ Vc, float* __restrict__ ao) {
  int s = blockIdx.x;
  int bh = blockIdx.y;  // b*8+h
  int b = bh >> 3, h = bh & 7;
  int lane = threadIdx.x;
  __shared__ __align__(16) float qs[DHEAD];
  __shared__ float sc[S_LEN];
  qs[lane] = qkv[((size_t)s * BATCH + b) * 1536 + h * DHEAD + lane];
  __syncthreads();
  int nk = s + 1;
  const float* kbase = Kc + (size_t)bh * S_LEN * DHEAD;
  const float4* q4 = (const float4*)qs;
  float lmax = -1e30f;
  for (int t = lane; t < nk; t += 64) {
    const float4* kp = (const float4*)(kbase + (size_t)t * DHEAD);
    float a = 0.f;
#pragma unroll
    for (int i = 0; i < 16; ++i) {
      float4 kk = kp[i]; float4 qq = q4[i];
      a += qq.x * kk.x + qq.y * kk.y + qq.z * kk.z + qq.w * kk.w;
    }
    a *= 0.125f;
    sc[t] = a;
    lmax = fmaxf(lmax, a);
  }
#pragma unroll
  for (int off = 32; off >= 1; off >>= 1) lmax = fmaxf(lmax, __shfl_xor(lmax, off));
  float lsum = 0.f;
  for (int t = lane; t < nk; t += 64) {
    float e = __expf(sc[t] - lmax);
    sc[t] = e;
    lsum += e;
  }
#pragma unroll
  for (int off = 32; off >= 1; off >>= 1) lsum += __shfl_xor(lsum, off);
  __syncthreads();
  float inv = __fdividef(1.f, lsum);
  const float* vb = Vc + (size_t)bh * S_LEN * DHEAD + lane;
  float o = 0.f;
  int t = 0;
  for (; t + 4 <= nk; t += 4) {
    float p0 = sc[t], p1 = sc[t + 1], p2 = sc[t + 2], p3 = sc[t + 3];
    float v0 = vb[(size_t)t * DHEAD], v1 = vb[(size_t)(t + 1) * DHEAD];
    float v2 = vb[(size_t)(t + 2) * DHEAD], v3 = vb[(size_t)(t + 3) * DHEAD];
    o += p0 * v0 + p1 * v1 + p2 * v2 + p3 * v3;
  }
  for (; t < nk; ++t) o += sc[t] * vb[(size_t)t * DHEAD];
  ao[((size_t)s * BATCH + b) * EMB + h * DHEAD + lane] = o * inv;
}

// --------- layernorm over E=512 of (xa+xb), optional nonsat ------------------
__global__ __launch_bounds__(256)
void ln_kernel(const float* __restrict__ xa, const float* __restrict__ xb,
               const float* __restrict__ g, const float* __restrict__ bet,
               float* __restrict__ out, int act) {
  int row = blockIdx.x;
  int t = threadIdx.x;
  size_t base = (size_t)row * EMB;
  float v0 = xa[base + t] + xb[base + t];
  float v1 = xa[base + t + 256] + xb[base + t + 256];
  float s = v0 + v1;
  float s2 = v0 * v0 + v1 * v1;
#pragma unroll
  for (int off = 32; off >= 1; off >>= 1) {
    s += __shfl_xor(s, off);
    s2 += __shfl_xor(s2, off);
  }
  __shared__ float ss[4], ss2[4];
  int w = t >> 6;
  if ((t & 63) == 0) { ss[w] = s; ss2[w] = s2; }
  __syncthreads();
  s = ss[0] + ss[1] + ss[2] + ss[3];
  s2 = ss2[0] + ss2[1] + ss2[2] + ss2[3];
  float mu = s * (1.f / EMB);
  float var = s2 * (1.f / EMB) - mu * mu;
  float rs = rsqrtf(var + 1e-5f);
  float o0 = (v0 - mu) * rs * g[t] + bet[t];
  float o1 = (v1 - mu) * rs * g[t + 256] + bet[t + 256];
  if (act) { o0 = nonsat_f(o0); o1 = nonsat_f(o1); }
  out[base + t] = o0;
  out[base + t + 256] = o1;
}

// --------- softmax over 128 (one wave per row) -------------------------------
__global__ __launch_bounds__(256)
void softmax128_kernel(float* __restrict__ L) {
  int row = blockIdx.x * 4 + (threadIdx.x >> 6);
  int lane = threadIdx.x & 63;
  float* p = L + (size_t)row * DSS;
  float a = p[lane], c = p[lane + 64];
  float m = fmaxf(a, c);
#pragma unroll
  for (int off = 32; off >= 1; off >>= 1) m = fmaxf(m, __shfl_xor(m, off));
  float e0 = __expf(a - m), e1 = __expf(c - m);
  float ssum = e0 + e1;
#pragma unroll
  for (int off = 32; off >= 1; off >>= 1) ssum += __shfl_xor(ssum, off);
  float inv = __fdividef(1.f, ssum);
  p[lane] = e0 * inv;
  p[lane + 64] = e1 * inv;
}

// --------- x2 = 0.5*(x1 + y) -------------------------------------------------
__global__ __launch_bounds__(256)
void avg_kernel(const float* __restrict__ a, const float* __restrict__ b,
                float* __restrict__ o) {
  int i = blockIdx.x * 256 + threadIdx.x;
  float4 x = ((const float4*)a)[i], y = ((const float4*)b)[i];
  float4 r = make_float4(0.5f * (x.x + y.x), 0.5f * (x.y + y.y),
                         0.5f * (x.z + y.z), 0.5f * (x.w + y.w));
  ((float4*)o)[i] = r;
}

// --------- controls = softmax3(hidden @ A_w^T + A_b), one wave per row -------
__global__ __launch_bounds__(256)
void controls_kernel(const float* __restrict__ hidden, const float* __restrict__ Aw,
                     const float* __restrict__ Ab, float* __restrict__ ctrl) {
  int row = blockIdx.x * 4 + (threadIdx.x >> 6);
  int lane = threadIdx.x & 63;
  const float* h = hidden + (size_t)row * DHID;
  float h0 = h[lane], h1 = h[lane + 64], h2 = h[lane + 128], h3 = h[lane + 192];
  float p0 = h0 * Aw[lane] + h1 * Aw[lane + 64] + h2 * Aw[lane + 128] + h3 * Aw[lane + 192];
  float p1 = h0 * Aw[256 + lane] + h1 * Aw[320 + lane] + h2 * Aw[384 + lane] + h3 * Aw[448 + lane];
  float p2 = h0 * Aw[512 + lane] + h1 * Aw[576 + lane] + h2 * Aw[640 + lane] + h3 * Aw[704 + lane];
#pragma unroll
  for (int off = 32; off >= 1; off >>= 1) {
    p0 += __shfl_xor(p0, off);
    p1 += __shfl_xor(p1, off);
    p2 += __shfl_xor(p2, off);
  }
  if (lane == 0) {
    p0 += Ab[0]; p1 += Ab[1]; p2 += Ab[2];
    float m = fmaxf(p0, fmaxf(p1, p2));
    float e0 = __expf(p0 - m), e1 = __expf(p1 - m), e2 = __expf(p2 - m);
    float inv = __fdividef(1.f, e0 + e1 + e2);
    ctrl[(size_t)row * 3 + 0] = e0 * inv;
    ctrl[(size_t)row * 3 + 1] = e1 * inv;
    ctrl[(size_t)row * 3 + 2] = e2 * inv;
  }
}

// --------- stack update: one block per (b,s) row -----------------------------
__global__ __launch_bounds__(256)
void stack_kernel(const float* __restrict__ sp, const float* __restrict__ si,
                  const float* __restrict__ ctrl, float* __restrict__ out) {
  int row = blockIdx.x;  // b*S+s
  float c0 = ctrl[(size_t)row * 3 + 0];
  float c1 = ctrl[(size_t)row * 3 + 1];
  float c2 = ctrl[(size_t)row * 3 + 2];
  const float4* spr = (const float4*)(sp + (size_t)row * SDEPTH * SWIDTH);
  const float4* sir = (const float4*)(si + (size_t)row * SWIDTH);
  float4* o = (float4*)(out + (size_t)row * SDEPTH * SWIDTH);
  const int WV = SWIDTH / 4;  // 24
  for (int i = threadIdx.x; i < SDEPTH * WV; i += 256) {
    int d = i / WV;
    int w = i - d * WV;
    float4 cur = spr[i];
    float4 up = (d == 0) ? sir[w] : spr[i - WV];
    float4 dn = (d < SDEPTH - 1) ? spr[i + WV] : make_float4(0.f, 0.f, 0.f, 0.f);
    float4 r;
    r.x = c2 * cur.x + c0 * up.x + c1 * dn.x;
    r.y = c2 * cur.y + c0 * up.y + c1 * dn.y;
    r.z = c2 * cur.z + c0 * up.z + c1 * dn.z;
    r.w = c2 * cur.w + c0 * up.w + c1 * dn.w;
    o[i] = r;
  }
}

static inline void gemm(hipStream_t st, const float* A, int lda, int perm,
                        const float* W, int ldw, const float* bias, float* C,
                        int M, int N, int K, int flags) {
  dim3 g((N + 63) / 64, M / 64);
  hipLaunchKernelGGL(gemm_kernel, g, dim3(256), 0, st, A, lda, perm, W, ldw,
                     bias, C, M, N, K, flags);
}

extern "C" void kernel_launch(void* const* d_in, const int* in_sizes, int n_in,
                              void* d_out, int out_size, void* d_ws, size_t ws_size,
                              hipStream_t stream) {
  const float* x_in  = (const float*)d_in[0];
  const float* hprev = (const float*)d_in[1];
  const float* sprev = (const float*)d_in[2];
  const float* ipw   = (const float*)d_in[3];
  const float* ipb   = (const float*)d_in[4];
  const float* opw   = (const float*)d_in[5];
  const float* opb   = (const float*)d_in[6];
  const float* ln1g  = (const float*)d_in[7];
  const float* ln1b  = (const float*)d_in[8];
  const float* ln2g  = (const float*)d_in[9];
  const float* ln2b  = (const float*)d_in[10];
  const float* Ww    = (const float*)d_in[11];
  const float* Wb    = (const float*)d_in[12];
  const float* Rw    = (const float*)d_in[13];
  const float* Rb    = (const float*)d_in[14];
  const float* Pw    = (const float*)d_in[15];
  const float* Pb    = (const float*)d_in[16];
  const float* Vw    = (const float*)d_in[17];
  const float* Uw    = (const float*)d_in[18];
  const float* Aw    = (const float*)d_in[19];
  const float* Ab    = (const float*)d_in[20];
  const float* Dw    = (const float*)d_in[21];
  const float* Db    = (const float*)d_in[22];
  const float* ffiw  = (const float*)d_in[23];
  const float* ffib  = (const float*)d_in[24];
  const float* ffow  = (const float*)d_in[25];
  const float* ffob  = (const float*)d_in[26];

  // workspace layout (floats); timeline reuse: qkv/Kc region later holds ff1,
  // bufB holds AO -> Y -> FO, bufC holds proj -> x2.
  float* ws     = (float*)d_ws;
  float* qkv    = ws;               // 12,582,912
  float* Kc     = ws + 12582912;    //  4,194,304
  float* Vc     = ws + 16777216;    //  4,194,304
  float* ff1    = ws;               // 16,777,216 (after attention done)
  float* bufB   = ws + 20971520;    //  4,194,304
  float* bufC   = ws + 25165824;    //  4,194,304
  float* x1     = ws + 29360128;    //  4,194,304
  float* logits = ws + 33554432;    //  1,048,576
  float* si     = ws + 34603008;    //    786,432
  float* ctrl   = ws + 35389440;    //     24,576   (total 141.7 MB)

  float* out_x = (float*)d_out;
  float* out_h = out_x + 4194304;
  float* out_s = out_h + 2097152;

  const int M = S_LEN * BATCH;  // 8192

  // 1. qkv projection
  gemm(stream, x_in, EMB, 0, ipw, EMB, ipb, qkv, M, 3 * EMB, EMB, 0);
  // 2. repack K/V contiguous per (b,h)
  hipLaunchKernelGGL(repack_kv, dim3(4096), dim3(256), 0, stream, qkv, Kc, Vc);
  // 3. causal attention -> bufB (pre-out_proj)
  hipLaunchKernelGGL(attn_kernel, dim3(S_LEN, BATCH * NHEAD), dim3(64), 0, stream,
                     qkv, Kc, Vc, bufB);
  // 4. out projection -> bufC
  gemm(stream, bufB, EMB, 0, opw, EMB, opb, bufC, M, EMB, EMB, 0);
  // 5. x1 = nonsat(LN(x_in + proj))
  hipLaunchKernelGGL(ln_kernel, dim3(M), dim3(256), 0, stream, x_in, bufC, ln1g,
                     ln1b, x1, 1);
  // 6. hidden = nonsat(x1'@W^T + Wb + hprev@R^T + Rb + stack0@P^T + Pb) -> d_out
  gemm(stream, x1, EMB, 1, Ww, EMB, Wb, out_h, M, DHID, EMB, 0);
  gemm(stream, hprev, DHID, 0, Rw, DHID, Rb, out_h, M, DHID, DHID, 1);
  gemm(stream, sprev, SDEPTH * SWIDTH, 0, Pw, SWIDTH, Pb, out_h, M, DHID, SWIDTH, 1 | 2);
  // 7. logits = [x1, hidden'] @ V^T
  gemm(stream, x1, EMB, 0, Vw, EMB + DHID, nullptr, logits, M, DSS, EMB, 0);
  gemm(stream, out_h, DHID, 2, Vw + EMB, EMB + DHID, nullptr, logits, M, DSS, DHID, 1);
  // 8. softmax over 128
  hipLaunchKernelGGL(softmax128_kernel, dim3(M / 4), dim3(256), 0, stream, logits);
  // 9. y = probs @ U^T -> bufB
  gemm(stream, logits, DSS, 0, Uw, DSS, nullptr, bufB, M, EMB, DSS, 0);
  // 10. x2 = 0.5*(x1 + y) -> bufC
  hipLaunchKernelGGL(avg_kernel, dim3(4096), dim3(256), 0, stream, x1, bufB, bufC);
  // 11. stack_inp = nonsat(hidden @ D^T + Db)
  gemm(stream, out_h, DHID, 0, Dw, DHID, Db, si, M, SWIDTH, DHID, 2);
  // 12. controls
  hipLaunchKernelGGL(controls_kernel, dim3(M / 4), dim3(256), 0, stream, out_h, Aw, Ab, ctrl);
  // 13. stack update -> d_out
  hipLaunchKernelGGL(stack_kernel, dim3(M), dim3(256), 0, stream, sprev, si, ctrl, out_s);
  // 14. ff1 = nonsat(x2 @ ffi^T + ffib)   (reuses qkv/Kc region)
  gemm(stream, bufC, EMB, 0, ffiw, EMB, ffib, ff1, M, DFF, EMB, 2);
  // 15. ff2 -> bufB
  gemm(stream, ff1, DFF, 0, ffow, DFF, ffob, bufB, M, EMB, DFF, 0);
  // 16. x_out = LN(x2 + ff)
  hipLaunchKernelGGL(ln_kernel, dim3(M), dim3(256), 0, stream, bufC, bufB, ln2g,
                     ln2b, out_x, 0);
}

// Round 2
// 1813.058 us; speedup vs baseline: 1.5061x; 1.5061x over previous
//
#include <hip/hip_runtime.h>
#include <math.h>

#define S_LEN 1024
#define BATCH 8
#define EMB 512
#define NHEAD 8
#define DHEAD 64
#define DHID 256
#define SDEPTH 48
#define SWIDTH 96
#define DFF 2048
#define DSS 128

// nonsat(x): solve y^3/3 + y = x by Newton (the reference's fixed-point iteration
// IS Newton for this equation; fully converged root == reference within ~1e-6).
__device__ __forceinline__ float nonsat_f(float x) {
  float y = x;
#pragma unroll
  for (int i = 0; i < 20; ++i) {
    float y2 = y * y;
    y = __fdividef(0.6666666667f * y * y2 + x, y2 + 1.0f);
  }
  return y;
}

// ---------------- generic fp32 GEMM: C[M,N] (+)= A[M,K] @ W[N,K]^T + bias ----
// perm: 0 identity; 1: A row = ((m&1023)<<3)|(m>>10)  (C rows (b,s), A rows (s,b))
//       2: A row = ((m&7)<<10)|(m>>3)                 (C rows (s,b), A rows (b,s))
// flags: bit0 = accumulate into C, bit1 = nonsat epilogue
__global__ __launch_bounds__(256)
void gemm_kernel(const float* __restrict__ A, int lda, int perm,
                 const float* __restrict__ W, int ldw,
                 const float* __restrict__ bias,
                 float* __restrict__ C,
                 int M, int N, int K, int flags) {
  __shared__ float As[16][68];
  __shared__ float Ws[16][68];
  int t = threadIdx.x;
  int tx = t & 15, ty = t >> 4;
  int m0 = blockIdx.y * 64, n0 = blockIdx.x * 64;
  int lr = t >> 2, lk = (t & 3) << 2;

  int mrow = m0 + lr;
  int arow = mrow;
  if (perm == 1)      arow = ((mrow & 1023) << 3) | (mrow >> 10);
  else if (perm == 2) arow = ((mrow & 7) << 10) | (mrow >> 3);
  const float* Ap = A + (size_t)arow * lda + lk;
  int nrow = n0 + lr;
  const float* Wp = W + (size_t)nrow * ldw + lk;
  bool wok = nrow < N;

  float acc[4][4] = {{0.f}};

  for (int k0 = 0; k0 < K; k0 += 16) {
    float4 av = *(const float4*)(Ap + k0);
    float4 wv = wok ? *(const float4*)(Wp + k0) : make_float4(0.f, 0.f, 0.f, 0.f);
    __syncthreads();
    As[lk + 0][lr] = av.x; As[lk + 1][lr] = av.y;
    As[lk + 2][lr] = av.z; As[lk + 3][lr] = av.w;
    Ws[lk + 0][lr] = wv.x; Ws[lk + 1][lr] = wv.y;
    Ws[lk + 2][lr] = wv.z; Ws[lk + 3][lr] = wv.w;
    __syncthreads();
#pragma unroll
    for (int k = 0; k < 16; ++k) {
      float a0 = As[k][ty * 4 + 0], a1 = As[k][ty * 4 + 1];
      float a2 = As[k][ty * 4 + 2], a3 = As[k][ty * 4 + 3];
      float w0 = Ws[k][tx * 4 + 0], w1 = Ws[k][tx * 4 + 1];
      float w2 = Ws[k][tx * 4 + 2], w3 = Ws[k][tx * 4 + 3];
      acc[0][0] += a0 * w0; acc[0][1] += a0 * w1; acc[0][2] += a0 * w2; acc[0][3] += a0 * w3;
      acc[1][0] += a1 * w0; acc[1][1] += a1 * w1; acc[1][2] += a1 * w2; acc[1][3] += a1 * w3;
      acc[2][0] += a2 * w0; acc[2][1] += a2 * w1; acc[2][2] += a2 * w2; acc[2][3] += a2 * w3;
      acc[3][0] += a3 * w0; acc[3][1] += a3 * w1; acc[3][2] += a3 * w2; acc[3][3] += a3 * w3;
    }
  }
#pragma unroll
  for (int i = 0; i < 4; ++i) {
    int m = m0 + ty * 4 + i;
#pragma unroll
    for (int j = 0; j < 4; ++j) {
      int n = n0 + tx * 4 + j;
      if (n < N) {
        float o = acc[i][j];
        if (bias) o += bias[n];
        size_t idx = (size_t)m * N + n;
        if (flags & 1) o += C[idx];
        if (flags & 2) o = nonsat_f(o);
        C[idx] = o;
      }
    }
  }
}

// --------- repack Q,K,V from qkv (s,b,1536) into per-(b,h) contiguous slabs --
__global__ __launch_bounds__(256)
void repack_qkv(const float* __restrict__ qkv, float* __restrict__ Qc,
                float* __restrict__ Kc, float* __restrict__ Vc) {
  int i = blockIdx.x * 256 + threadIdx.x;  // float4 index, 1048576 total
  int d4 = i & 15;
  int t  = (i >> 4) & 1023;
  int h  = (i >> 14) & 7;
  int b  = i >> 17;
  const float4* src = (const float4*)qkv;
  size_t base = ((size_t)t * BATCH + b) * 384 + h * 16 + d4;
  size_t out  = (size_t)i;  // == ((b*8+h)*1024 + t)*16 + d4
  ((float4*)Qc)[out] = src[base];
  ((float4*)Kc)[out] = src[base + 128];
  ((float4*)Vc)[out] = src[base + 256];
}

// --------- flash-style causal attention -------------------------------------
// One 256-thread block per (64-query tile, b*h). K/V tiles in LDS, online
// softmax, P round-trips through LDS transposed so both GEMM phases use
// contiguous (b128) LDS reads. Thread (ty,tx) owns the 4x4 fragment
// [query ty*4+i][key/dim tx*4+j].
__global__ __launch_bounds__(256)
void fattn_kernel(const float* __restrict__ Qc, const float* __restrict__ Kc,
                  const float* __restrict__ Vc, float* __restrict__ ao) {
  int qi = blockIdx.x;   // query tile 0..15
  int bh = blockIdx.y;   // b*8+h
  int b = bh >> 3, h = bh & 7;
  int t = threadIdx.x;
  int tx = t & 15, ty = t >> 4;

  __shared__ float Qs[64][68];  // [d][q], pre-scaled
  __shared__ float Ks[64][68];  // [d][k]; reused as Pt[k][q] after scores
  __shared__ float Vs[64][68];  // [k][d]

  const float* Qbase = Qc + ((size_t)bh * S_LEN + qi * 64) * DHEAD;
#pragma unroll
  for (int f = t, it = 0; it < 4; ++it, f += 256) {
    int r = f >> 4, c4 = (f & 15) << 2;
    float4 q = *(const float4*)(Qbase + r * DHEAD + c4);
    Qs[c4 + 0][r] = q.x * 0.125f;
    Qs[c4 + 1][r] = q.y * 0.125f;
    Qs[c4 + 2][r] = q.z * 0.125f;
    Qs[c4 + 3][r] = q.w * 0.125f;
  }

  float o[4][4] = {{0.f}};
  float m_i[4] = {-1e30f, -1e30f, -1e30f, -1e30f};
  float l_i[4] = {0.f, 0.f, 0.f, 0.f};

  for (int kt = 0; kt <= qi; ++kt) {
    const float* Kbase = Kc + ((size_t)bh * S_LEN + kt * 64) * DHEAD;
    const float* Vbase = Vc + ((size_t)bh * S_LEN + kt * 64) * DHEAD;
    __syncthreads();  // previous tile's PV reads done
#pragma unroll
    for (int f = t, it = 0; it < 4; ++it, f += 256) {
      int r = f >> 4, c4 = (f & 15) << 2;
      float4 k4 = *(const float4*)(Kbase + r * DHEAD + c4);
      Ks[c4 + 0][r] = k4.x;
      Ks[c4 + 1][r] = k4.y;
      Ks[c4 + 2][r] = k4.z;
      Ks[c4 + 3][r] = k4.w;
      float4 v4 = *(const float4*)(Vbase + r * DHEAD + c4);
      *(float4*)&Vs[r][c4] = v4;
    }
    __syncthreads();

    float s[4][4] = {{0.f}};
#pragma unroll 16
    for (int d = 0; d < 64; ++d) {
      float a0 = Qs[d][ty * 4 + 0], a1 = Qs[d][ty * 4 + 1];
      float a2 = Qs[d][ty * 4 + 2], a3 = Qs[d][ty * 4 + 3];
      float w0 = Ks[d][tx * 4 + 0], w1 = Ks[d][tx * 4 + 1];
      float w2 = Ks[d][tx * 4 + 2], w3 = Ks[d][tx * 4 + 3];
      s[0][0] += a0 * w0; s[0][1] += a0 * w1; s[0][2] += a0 * w2; s[0][3] += a0 * w3;
      s[1][0] += a1 * w0; s[1][1] += a1 * w1; s[1][2] += a1 * w2; s[1][3] += a1 * w3;
      s[2][0] += a2 * w0; s[2][1] += a2 * w1; s[2][2] += a2 * w2; s[2][3] += a2 * w3;
      s[3][0] += a3 * w0; s[3][1] += a3 * w1; s[3][2] += a3 * w2; s[3][3] += a3 * w3;
    }

    if (kt == qi) {  // causal mask on diagonal tile
#pragma unroll
      for (int i = 0; i < 4; ++i)
#pragma unroll
        for (int j = 0; j < 4; ++j)
          if (tx * 4 + j > ty * 4 + i) s[i][j] = -1e30f;
    }

    float p[4][4];
    float alpha[4], rsum[4];
#pragma unroll
    for (int i = 0; i < 4; ++i) {
      float rmax = fmaxf(fmaxf(s[i][0], s[i][1]), fmaxf(s[i][2], s[i][3]));
      rmax = fmaxf(rmax, __shfl_xor(rmax, 1));
      rmax = fmaxf(rmax, __shfl_xor(rmax, 2));
      rmax = fmaxf(rmax, __shfl_xor(rmax, 4));
      rmax = fmaxf(rmax, __shfl_xor(rmax, 8));
      float mn = fmaxf(m_i[i], rmax);
      alpha[i] = __expf(m_i[i] - mn);
      m_i[i] = mn;
      float rs = 0.f;
#pragma unroll
      for (int j = 0; j < 4; ++j) {
        p[i][j] = __expf(s[i][j] - mn);
        rs += p[i][j];
      }
      rs += __shfl_xor(rs, 1);
      rs += __shfl_xor(rs, 2);
      rs += __shfl_xor(rs, 4);
      rs += __shfl_xor(rs, 8);
      rsum[i] = rs;
    }
#pragma unroll
    for (int i = 0; i < 4; ++i) {
      l_i[i] = l_i[i] * alpha[i] + rsum[i];
#pragma unroll
      for (int j = 0; j < 4; ++j) o[i][j] *= alpha[i];
    }

    __syncthreads();  // all score reads of Ks done
    // store P transposed: Pt[k][q] in the Ks buffer (float4 along q)
#pragma unroll
    for (int j = 0; j < 4; ++j) {
      float4 pj = make_float4(p[0][j], p[1][j], p[2][j], p[3][j]);
      *(float4*)&Ks[tx * 4 + j][ty * 4] = pj;
    }
    __syncthreads();

#pragma unroll 16
    for (int k = 0; k < 64; ++k) {
      float a0 = Ks[k][ty * 4 + 0], a1 = Ks[k][ty * 4 + 1];
      float a2 = Ks[k][ty * 4 + 2], a3 = Ks[k][ty * 4 + 3];
      float v0 = Vs[k][tx * 4 + 0], v1 = Vs[k][tx * 4 + 1];
      float v2 = Vs[k][tx * 4 + 2], v3 = Vs[k][tx * 4 + 3];
      o[0][0] += a0 * v0; o[0][1] += a0 * v1; o[0][2] += a0 * v2; o[0][3] += a0 * v3;
      o[1][0] += a1 * v0; o[1][1] += a1 * v1; o[1][2] += a1 * v2; o[1][3] += a1 * v3;
      o[2][0] += a2 * v0; o[2][1] += a2 * v1; o[2][2] += a2 * v2; o[2][3] += a2 * v3;
      o[3][0] += a3 * v0; o[3][1] += a3 * v1; o[3][2] += a3 * v2; o[3][3] += a3 * v3;
    }
  }

#pragma unroll
  for (int i = 0; i < 4; ++i) {
    float inv = __fdividef(1.f, l_i[i]);
    int s_glob = qi * 64 + ty * 4 + i;
    float4 r = make_float4(o[i][0] * inv, o[i][1] * inv, o[i][2] * inv, o[i][3] * inv);
    *(float4*)(ao + ((size_t)s_glob * BATCH + b) * EMB + h * DHEAD + tx * 4) = r;
  }
}

// --------- layernorm over E=512 of (xa+xb), optional nonsat ------------------
__global__ __launch_bounds__(256)
void ln_kernel(const float* __restrict__ xa, const float* __restrict__ xb,
               const float* __restrict__ g, const float* __restrict__ bet,
               float* __restrict__ out, int act) {
  int row = blockIdx.x;
  int t = threadIdx.x;
  size_t base = (size_t)row * EMB;
  float v0 = xa[base + t] + xb[base + t];
  float v1 = xa[base + t + 256] + xb[base + t + 256];
  float s = v0 + v1;
  float s2 = v0 * v0 + v1 * v1;
#pragma unroll
  for (int off = 32; off >= 1; off >>= 1) {
    s += __shfl_xor(s, off);
    s2 += __shfl_xor(s2, off);
  }
  __shared__ float ss[4], ss2[4];
  int w = t >> 6;
  if ((t & 63) == 0) { ss[w] = s; ss2[w] = s2; }
  __syncthreads();
  s = ss[0] + ss[1] + ss[2] + ss[3];
  s2 = ss2[0] + ss2[1] + ss2[2] + ss2[3];
  float mu = s * (1.f / EMB);
  float var = s2 * (1.f / EMB) - mu * mu;
  float rs = rsqrtf(var + 1e-5f);
  float o0 = (v0 - mu) * rs * g[t] + bet[t];
  float o1 = (v1 - mu) * rs * g[t + 256] + bet[t + 256];
  if (act) { o0 = nonsat_f(o0); o1 = nonsat_f(o1); }
  out[base + t] = o0;
  out[base + t + 256] = o1;
}

// --------- softmax over 128 (one wave per row) -------------------------------
__global__ __launch_bounds__(256)
void softmax128_kernel(float* __restrict__ L) {
  int row = blockIdx.x * 4 + (threadIdx.x >> 6);
  int lane = threadIdx.x & 63;
  float* p = L + (size_t)row * DSS;
  float a = p[lane], c = p[lane + 64];
  float m = fmaxf(a, c);
#pragma unroll
  for (int off = 32; off >= 1; off >>= 1) m = fmaxf(m, __shfl_xor(m, off));
  float e0 = __expf(a - m), e1 = __expf(c - m);
  float ssum = e0 + e1;
#pragma unroll
  for (int off = 32; off >= 1; off >>= 1) ssum += __shfl_xor(ssum, off);
  float inv = __fdividef(1.f, ssum);
  p[lane] = e0 * inv;
  p[lane + 64] = e1 * inv;
}

// --------- x2 = 0.5*(x1 + y) -------------------------------------------------
__global__ __launch_bounds__(256)
void avg_kernel(const float* __restrict__ a, const float* __restrict__ b,
                float* __restrict__ o) {
  int i = blockIdx.x * 256 + threadIdx.x;
  float4 x = ((const float4*)a)[i], y = ((const float4*)b)[i];
  float4 r = make_float4(0.5f * (x.x + y.x), 0.5f * (x.y + y.y),
                         0.5f * (x.z + y.z), 0.5f * (x.w + y.w));
  ((float4*)o)[i] = r;
}

// --------- controls = softmax3(hidden @ A_w^T + A_b), one wave per row -------
__global__ __launch_bounds__(256)
void controls_kernel(const float* __restrict__ hidden, const float* __restrict__ Aw,
                     const float* __restrict__ Ab, float* __restrict__ ctrl) {
  int row = blockIdx.x * 4 + (threadIdx.x >> 6);
  int lane = threadIdx.x & 63;
  const float* h = hidden + (size_t)row * DHID;
  float h0 = h[lane], h1 = h[lane + 64], h2 = h[lane + 128], h3 = h[lane + 192];
  float p0 = h0 * Aw[lane] + h1 * Aw[lane + 64] + h2 * Aw[lane + 128] + h3 * Aw[lane + 192];
  float p1 = h0 * Aw[256 + lane] + h1 * Aw[320 + lane] + h2 * Aw[384 + lane] + h3 * Aw[448 + lane];
  float p2 = h0 * Aw[512 + lane] + h1 * Aw[576 + lane] + h2 * Aw[640 + lane] + h3 * Aw[704 + lane];
#pragma unroll
  for (int off = 32; off >= 1; off >>= 1) {
    p0 += __shfl_xor(p0, off);
    p1 += __shfl_xor(p1, off);
    p2 += __shfl_xor(p2, off);
  }
  if (lane == 0) {
    p0 += Ab[0]; p1 += Ab[1]; p2 += Ab[2];
    float m = fmaxf(p0, fmaxf(p1, p2));
    float e0 = __expf(p0 - m), e1 = __expf(p1 - m), e2 = __expf(p2 - m);
    float inv = __fdividef(1.f, e0 + e1 + e2);
    ctrl[(size_t)row * 3 + 0] = e0 * inv;
    ctrl[(size_t)row * 3 + 1] = e1 * inv;
    ctrl[(size_t)row * 3 + 2] = e2 * inv;
  }
}

// --------- stack update: one block per (b,s) row -----------------------------
__global__ __launch_bounds__(256)
void stack_kernel(const float* __restrict__ sp, const float* __restrict__ si,
                  const float* __restrict__ ctrl, float* __restrict__ out) {
  int row = blockIdx.x;  // b*S+s
  float c0 = ctrl[(size_t)row * 3 + 0];
  float c1 = ctrl[(size_t)row * 3 + 1];
  float c2 = ctrl[(size_t)row * 3 + 2];
  const float4* spr = (const float4*)(sp + (size_t)row * SDEPTH * SWIDTH);
  const float4* sir = (const float4*)(si + (size_t)row * SWIDTH);
  float4* o = (float4*)(out + (size_t)row * SDEPTH * SWIDTH);
  const int WV = SWIDTH / 4;  // 24
  for (int i = threadIdx.x; i < SDEPTH * WV; i += 256) {
    int d = i / WV;
    int w = i - d * WV;
    float4 cur = spr[i];
    float4 up = (d == 0) ? sir[w] : spr[i - WV];
    float4 dn = (d < SDEPTH - 1) ? spr[i + WV] : make_float4(0.f, 0.f, 0.f, 0.f);
    float4 r;
    r.x = c2 * cur.x + c0 * up.x + c1 * dn.x;
    r.y = c2 * cur.y + c0 * up.y + c1 * dn.y;
    r.z = c2 * cur.z + c0 * up.z + c1 * dn.z;
    r.w = c2 * cur.w + c0 * up.w + c1 * dn.w;
    o[i] = r;
  }
}

static inline void gemm(hipStream_t st, const float* A, int lda, int perm,
                        const float* W, int ldw, const float* bias, float* C,
                        int M, int N, int K, int flags) {
  dim3 g((N + 63) / 64, M / 64);
  hipLaunchKernelGGL(gemm_kernel, g, dim3(256), 0, st, A, lda, perm, W, ldw,
                     bias, C, M, N, K, flags);
}

extern "C" void kernel_launch(void* const* d_in, const int* in_sizes, int n_in,
                              void* d_out, int out_size, void* d_ws, size_t ws_size,
                              hipStream_t stream) {
  const float* x_in  = (const float*)d_in[0];
  const float* hprev = (const float*)d_in[1];
  const float* sprev = (const float*)d_in[2];
  const float* ipw   = (const float*)d_in[3];
  const float* ipb   = (const float*)d_in[4];
  const float* opw   = (const float*)d_in[5];
  const float* opb   = (const float*)d_in[6];
  const float* ln1g  = (const float*)d_in[7];
  const float* ln1b  = (const float*)d_in[8];
  const float* ln2g  = (const float*)d_in[9];
  const float* ln2b  = (const float*)d_in[10];
  const float* Ww    = (const float*)d_in[11];
  const float* Wb    = (const float*)d_in[12];
  const float* Rw    = (const float*)d_in[13];
  const float* Rb    = (const float*)d_in[14];
  const float* Pw    = (const float*)d_in[15];
  const float* Pb    = (const float*)d_in[16];
  const float* Vw    = (const float*)d_in[17];
  const float* Uw    = (const float*)d_in[18];
  const float* Aw    = (const float*)d_in[19];
  const float* Ab    = (const float*)d_in[20];
  const float* Dw    = (const float*)d_in[21];
  const float* Db    = (const float*)d_in[22];
  const float* ffiw  = (const float*)d_in[23];
  const float* ffib  = (const float*)d_in[24];
  const float* ffow  = (const float*)d_in[25];
  const float* ffob  = (const float*)d_in[26];

  // workspace layout (floats); timeline reuse: qkv/Kc region later holds ff1,
  // bufB holds AO -> Y -> FO, bufC holds Qc -> proj -> x2.
  float* ws     = (float*)d_ws;
  float* qkv    = ws;               // 12,582,912
  float* Kc     = ws + 12582912;    //  4,194,304
  float* Vc     = ws + 16777216;    //  4,194,304
  float* ff1    = ws;               // 16,777,216 (after attention done)
  float* bufB   = ws + 20971520;    //  4,194,304
  float* bufC   = ws + 25165824;    //  4,194,304 (Qc until out-proj overwrites)
  float* x1     = ws + 29360128;    //  4,194,304
  float* logits = ws + 33554432;    //  1,048,576
  float* si     = ws + 34603008;    //    786,432
  float* ctrl   = ws + 35389440;    //     24,576   (total 141.7 MB)
  float* Qc     = bufC;

  float* out_x = (float*)d_out;
  float* out_h = out_x + 4194304;
  float* out_s = out_h + 2097152;

  const int M = S_LEN * BATCH;  // 8192

  // 1. qkv projection
  gemm(stream, x_in, EMB, 0, ipw, EMB, ipb, qkv, M, 3 * EMB, EMB, 0);
  // 2. repack Q/K/V contiguous per (b,h)
  hipLaunchKernelGGL(repack_qkv, dim3(4096), dim3(256), 0, stream, qkv, Qc, Kc, Vc);
  // 3. flash causal attention -> bufB (pre-out_proj)
  hipLaunchKernelGGL(fattn_kernel, dim3(S_LEN / 64, BATCH * NHEAD), dim3(256), 0,
                     stream, Qc, Kc, Vc, bufB);
  // 4. out projection -> bufC
  gemm(stream, bufB, EMB, 0, opw, EMB, opb, bufC, M, EMB, EMB, 0);
  // 5. x1 = nonsat(LN(x_in + proj))
  hipLaunchKernelGGL(ln_kernel, dim3(M), dim3(256), 0, stream, x_in, bufC, ln1g,
                     ln1b, x1, 1);
  // 6. hidden = nonsat(x1'@W^T + Wb + hprev@R^T + Rb + stack0@P^T + Pb) -> d_out
  gemm(stream, x1, EMB, 1, Ww, EMB, Wb, out_h, M, DHID, EMB, 0);
  gemm(stream, hprev, DHID, 0, Rw, DHID, Rb, out_h, M, DHID, DHID, 1);
  gemm(stream, sprev, SDEPTH * SWIDTH, 0, Pw, SWIDTH, Pb, out_h, M, DHID, SWIDTH, 1 | 2);
  // 7. logits = [x1, hidden'] @ V^T
  gemm(stream, x1, EMB, 0, Vw, EMB + DHID, nullptr, logits, M, DSS, EMB, 0);
  gemm(stream, out_h, DHID, 2, Vw + EMB, EMB + DHID, nullptr, logits, M, DSS, DHID, 1);
  // 8. softmax over 128
  hipLaunchKernelGGL(softmax128_kernel, dim3(M / 4), dim3(256), 0, stream, logits);
  // 9. y = probs @ U^T -> bufB
  gemm(stream, logits, DSS, 0, Uw, DSS, nullptr, bufB, M, EMB, DSS, 0);
  // 10. x2 = 0.5*(x1 + y) -> bufC
  hipLaunchKernelGGL(avg_kernel, dim3(4096), dim3(256), 0, stream, x1, bufB, bufC);
  // 11. stack_inp = nonsat(hidden @ D^T + Db)
  gemm(stream, out_h, DHID, 0, Dw, DHID, Db, si, M, SWIDTH, DHID, 2);
  // 12. controls
  hipLaunchKernelGGL(controls_kernel, dim3(M / 4), dim3(256), 0, stream, out_h, Aw, Ab, ctrl);
  // 13. stack update -> d_out
  hipLaunchKernelGGL(stack_kernel, dim3(M), dim3(256), 0, stream, sprev, si, ctrl, out_s);
  // 14. ff1 = nonsat(x2 @ ffi^T + ffib)   (reuses qkv/Kc region)
  gemm(stream, bufC, EMB, 0, ffiw, EMB, ffib, ff1, M, DFF, EMB, 2);
  // 15. ff2 -> bufB
  gemm(stream, ff1, DFF, 0, ffow, DFF, ffob, bufB, M, EMB, DFF, 0);
  // 16. x_out = LN(x2 + ff)
  hipLaunchKernelGGL(ln_kernel, dim3(M), dim3(256), 0, stream, bufC, bufB, ln2g,
                     ln2b, out_x, 0);
}